// Round 6
// baseline (635.735 us; speedup 1.0000x reference)
//
#include <hip/hip_runtime.h>
#include <hip/hip_bf16.h>
#include <stdint.h>

#define NNODES 100000
#define NEDGES 1000000
#define DIM 64
#define NRELS 16
#define EPB 2048
#define NB ((NEDGES + EPB - 1) / EPB)   /* 489 */
#define PADCAP (NEDGES + NRELS * 64)    /* 1001024 */
#define MAXTILES (PADCAP / 64)          /* 15641 */
#define NDN NNODES
#define BKT 256                          /* nodes per dst bucket */
#define NBKT ((NDN + BKT - 1) / BKT)     /* 391 */

// setup grid split
#define FEAT_BLKS 6250
#define W_BLKS 256
#define SETUP_BLKS (FEAT_BLKS + W_BLKS + NB)

// ws layout (bytes):
//   featB   @ 0          : ushort[NNODES*64]   -> 12,800,000
//   Wt      @ 12800000   : ushort[16*64*64]    -> 12,931,072
//   hist16  @ 12931072   : int[NB*16]          -> 12,963,840 (reserve)
//   bbase16 @ 12963840   : int[NB*16]          -> 12,996,608
//   Pve     @ 12996608   : int[33]             -> 12,996,864
//   hist391 @ 12996864   : int[NB*NBKT]        -> 13,764,864 (reserve 768,000)
//   bbase391@ 13764864   : int[NB*NBKT]        -> 14,532,864
//   bstart  @ 14532864   : int[NBKT+1]         -> 14,534,464 (reserve 1,600)
//   dloc    @ 14534464   : ushort[NEDGES]      -> 16,534,464
//   pairE   @ 16534464   : int2[PADCAP]        -> 24,542,656  {src, bpos|dst}
//   msgE    @ 24542656   : ushort[NEDGES*64]   -> 152,542,656
#define WS_NEED 152542656ull

using short8  = __attribute__((ext_vector_type(8))) short;
using floatx4 = __attribute__((ext_vector_type(4))) float;
using uintx4  = __attribute__((ext_vector_type(4))) unsigned int;

__device__ __forceinline__ unsigned short f2bf(float f) {
    union { float f; uint32_t u; } v; v.f = f;
    uint32_t u = v.u;
    return (unsigned short)((u + 0x7FFFu + ((u >> 16) & 1u)) >> 16);
}
__device__ __forceinline__ float bf2f(uint32_t u16) {
    union { uint32_t u; float f; } v; v.u = u16 << 16;
    return v.f;
}
__device__ __forceinline__ uint32_t pk2(float a, float b) {
    __hip_bfloat162 h = __float22bfloat162_rn(make_float2(a, b));
    union { __hip_bfloat162 h; uint32_t u; } v; v.h = h;
    return v.u;
}

// fused setup: feat->bf16, W->bf16 transposed, per-block rel hist + dst-bucket hist.
// NO global atomics anywhere.
__global__ void k_setup(const float* __restrict__ feat, const float* __restrict__ W,
                        const int* __restrict__ et, const int* __restrict__ dst,
                        unsigned short* __restrict__ featB, unsigned short* __restrict__ Wt,
                        int* __restrict__ hist16, int* __restrict__ hist391) {
    __shared__ int cnt16[16];
    __shared__ int cnt391[NBKT];
    const int b = blockIdx.x;
    if (b < FEAT_BLKS) {
        int i = (b * 256 + threadIdx.x) * 4;
        const float4 f = *(const float4*)(feat + i);
        ushort4 o;
        o.x = f2bf(f.x); o.y = f2bf(f.y); o.z = f2bf(f.z); o.w = f2bf(f.w);
        *(ushort4*)(featB + i) = o;
    } else if (b < FEAT_BLKS + W_BLKS) {
        int t = (b - FEAT_BLKS) * 256 + threadIdx.x;   // 65536 total
        int r = t >> 12, n = (t >> 6) & 63, k = t & 63;
        Wt[t] = f2bf(W[(r << 12) + (k << 6) + n]);     // Wt[r][n][k] = W[r][k][n]
    } else {
        const int bb = b - (FEAT_BLKS + W_BLKS);
        if (threadIdx.x < 16) cnt16[threadIdx.x] = 0;
        for (int t = threadIdx.x; t < NBKT; t += 256) cnt391[t] = 0;
        __syncthreads();
        int start = bb * EPB;
        int end = min(NEDGES, start + EPB);
        for (int i = start + threadIdx.x; i < end; i += 256) {
            atomicAdd(&cnt16[et[i]], 1);
            atomicAdd(&cnt391[dst[i] >> 8], 1);
        }
        __syncthreads();
        if (threadIdx.x < 16) hist16[bb * 16 + threadIdx.x] = cnt16[threadIdx.x];
        for (int t = threadIdx.x; t < NBKT; t += 256)
            hist391[bb * NBKT + t] = cnt391[t];
    }
}

// relation scan: 16 waves, wave w scans relation w over NB blocks
__global__ void k_scan(const int* __restrict__ hist, int* __restrict__ bbase,
                       int* __restrict__ Pve) {
    __shared__ int s_cnt[16];
    __shared__ int s_P[17];
    int w = threadIdx.x >> 6;
    int lane = threadIdx.x & 63;
    int carry = 0;
    for (int c = 0; c < NB; c += 64) {
        int idx = c + lane;
        int v = (idx < NB) ? hist[idx * 16 + w] : 0;
        int x = v;
        #pragma unroll
        for (int off = 1; off < 64; off <<= 1) {
            int y = __shfl_up(x, off);
            if (lane >= off) x += y;
        }
        if (idx < NB) bbase[idx * 16 + w] = carry + x - v;
        carry += __shfl(x, 63);
    }
    if (lane == 0) s_cnt[w] = carry;
    __syncthreads();
    if (threadIdx.x == 0) {
        int p = 0;
        for (int r = 0; r < 16; ++r) {
            s_P[r] = p;
            Pve[r] = p;
            Pve[17 + r] = p + s_cnt[r];
            p += (s_cnt[r] + 63) & ~63;
        }
        s_P[16] = p;
        Pve[16] = p;
    }
    __syncthreads();
    int pw = s_P[w];
    for (int idx = lane; idx < NB; idx += 64)
        bbase[idx * 16 + w] += pw;
}

// bucket scan A: one wave per bucket, exclusive over NB blocks; totals -> bstart[b]
__global__ void k_bscanA(const int* __restrict__ hist391, int* __restrict__ bbase391,
                         int* __restrict__ bstart) {
    int b = blockIdx.x * 4 + (threadIdx.x >> 6);
    int lane = threadIdx.x & 63;
    if (b >= NBKT) return;
    int carry = 0;
    for (int c = 0; c < NB; c += 64) {
        int idx = c + lane;
        int v = (idx < NB) ? hist391[idx * NBKT + b] : 0;
        int x = v;
        #pragma unroll
        for (int off = 1; off < 64; off <<= 1) {
            int y = __shfl_up(x, off);
            if (lane >= off) x += y;
        }
        if (idx < NB) bbase391[idx * NBKT + b] = carry + x - v;
        carry += __shfl(x, 63);
    }
    if (lane == 0) bstart[b] = carry;   // totals; exclusive-scanned in k_bscanB
}

// bucket scan B: tiny serial prefix over NBKT totals
__global__ void k_bscanB(int* __restrict__ bstart) {
    if (threadIdx.x == 0) {
        int run = 0;
        for (int b = 0; b < NBKT; ++b) {
            int t = bstart[b];
            bstart[b] = run;
            run += t;
        }
        bstart[NBKT] = run;
    }
}

// pairE[pos] = {src, bpos} (phases) or {src, dst} (fallback); dloc[bpos] = dst&255.
// Only LDS atomics.
__global__ void k_scatter(const int* __restrict__ et, const int* __restrict__ src,
                          const int* __restrict__ dst, const int* __restrict__ bbase16,
                          const int* __restrict__ bbase391, const int* __restrict__ bstart,
                          int2* __restrict__ pairE, unsigned short* __restrict__ dloc,
                          int buildPos) {
    __shared__ int base16[16];
    __shared__ int base391[NBKT];
    if (threadIdx.x < 16) base16[threadIdx.x] = bbase16[blockIdx.x * 16 + threadIdx.x];
    if (buildPos)
        for (int t = threadIdx.x; t < NBKT; t += 256)
            base391[t] = bbase391[blockIdx.x * NBKT + t] + bstart[t];
    __syncthreads();
    int start = blockIdx.x * EPB;
    int end = min(NEDGES, start + EPB);
    for (int i = start + threadIdx.x; i < end; i += 256) {
        int r = et[i];
        int pos = atomicAdd(&base16[r], 1);
        int d = dst[i];
        if (buildPos) {
            int bp = atomicAdd(&base391[d >> 8], 1);
            pairE[pos] = make_int2(src[i], bp);
            dloc[bp] = (unsigned short)(d & 255);
        } else {
            pairE[pos] = make_int2(src[i], d);
        }
    }
}

// Phase A: per 64-edge tile (single relation), GEMM -> bf16 msg row at bpos (NT stores)
__global__ void __launch_bounds__(256)
k_computeA(const unsigned short* __restrict__ featB,
           const unsigned short* __restrict__ Wt,
           const int2* __restrict__ pairE, const int* __restrict__ Pve,
           unsigned short* __restrict__ msgE) {
    __shared__ float lds[4][16 * 68];   // per-wave 16x64 transpose, stride 68
    const int w = threadIdx.x >> 6;
    const int t = blockIdx.x * 4 + w;
    const int base = t * 64;
    const int total = Pve[16];
    if (base >= total) return;
    int r = 0;
    while (base >= Pve[r + 1]) ++r;
    const int validEnd = Pve[17 + r];
    const int lane = threadIdx.x & 63;
    const int quad = lane >> 4;
    const int l16 = lane & 15;

    const unsigned short* wr = Wt + (r << 12);
    short8 bfr[4][2];
    #pragma unroll
    for (int tn = 0; tn < 4; ++tn)
        #pragma unroll
        for (int ks = 0; ks < 2; ++ks)
            bfr[tn][ks] = *(const short8*)(wr + ((tn * 16 + l16) << 6) + ks * 32 + quad * 8);

    const int rr = lane >> 2, seg = lane & 3;
    #pragma unroll
    for (int tm = 0; tm < 4; ++tm) {
        int row = base + tm * 16 + l16;
        int s = (row < validEnd) ? pairE[row].x : 0;
        const unsigned short* fp = featB + (s << 6) + quad * 8;
        short8 a0 = *(const short8*)(fp);
        short8 a1 = *(const short8*)(fp + 32);
        #pragma unroll
        for (int tn = 0; tn < 4; ++tn) {
            floatx4 c = {0.f, 0.f, 0.f, 0.f};
            c = __builtin_amdgcn_mfma_f32_16x16x32_bf16(a0, bfr[tn][0], c, 0, 0, 0);
            c = __builtin_amdgcn_mfma_f32_16x16x32_bf16(a1, bfr[tn][1], c, 0, 0, 0);
            #pragma unroll
            for (int j = 0; j < 4; ++j)
                lds[w][(quad * 4 + j) * 68 + tn * 16 + l16] = c[j];
        }
        // lane l handles output row (l>>2), 16-col segment (l&3)
        int rowi = base + tm * 16 + rr;
        int p = (rowi < validEnd) ? pairE[rowi].y : -1;
        if (p >= 0) {
            const float* lp = &lds[w][rr * 68 + seg * 16];
            uintx4 o0, o1;
            o0.x = pk2(lp[0],  lp[1]);  o0.y = pk2(lp[2],  lp[3]);
            o0.z = pk2(lp[4],  lp[5]);  o0.w = pk2(lp[6],  lp[7]);
            o1.x = pk2(lp[8],  lp[9]);  o1.y = pk2(lp[10], lp[11]);
            o1.z = pk2(lp[12], lp[13]); o1.w = pk2(lp[14], lp[15]);
            uintx4* op = (uintx4*)(msgE + (size_t)p * 64 + seg * 16);
            __builtin_nontemporal_store(o0, op);
            __builtin_nontemporal_store(o1, op + 1);
        }
    }
}

// Phase B: one block per 256-node bucket; 64 KB LDS fp32 accumulator,
// node-swizzled cols; stream bucket rows NT, ds-atomic accumulate, store once.
__global__ void __launch_bounds__(512)
k_reduce(const unsigned short* __restrict__ msgE,
         const unsigned short* __restrict__ dloc,
         const int* __restrict__ bstart, float* __restrict__ out) {
    __shared__ float acc[BKT * 64];     // 64 KiB
    const int b = blockIdx.x;
    for (int i = threadIdx.x; i < BKT * 64; i += 512) acc[i] = 0.f;
    __syncthreads();
    const int start = bstart[b], end = bstart[b + 1];
    const int wid = threadIdx.x >> 6;
    const int lane = threadIdx.x & 63;
    const int half = lane >> 5, l32 = lane & 31;
    const uint32_t* m32 = (const uint32_t*)msgE;
    for (int m = wid * 2 + half; start + m < end; m += 16) {
        int row = start + m;
        uint32_t v = __builtin_nontemporal_load(m32 + (size_t)row * 32 + l32);
        int node = dloc[row];
        int c0 = 2 * l32;
        atomicAdd(&acc[node * 64 + ((c0 + node) & 63)], bf2f(v & 0xffffu));
        atomicAdd(&acc[node * 64 + ((c0 + 1 + node) & 63)], bf2f(v >> 16));
    }
    __syncthreads();
    #pragma unroll
    for (int k = 0; k < 8; ++k) {
        int idx = k * 512 + threadIdx.x;       // 0..4095
        int node = idx >> 4;
        int c4 = (idx & 15) * 4;
        int g = b * BKT + node;
        if (g < NDN) {
            float4 o;
            o.x = acc[node * 64 + ((c4 + node) & 63)];
            o.y = acc[node * 64 + ((c4 + 1 + node) & 63)];
            o.z = acc[node * 64 + ((c4 + 2 + node) & 63)];
            o.w = acc[node * 64 + ((c4 + 3 + node) & 63)];
            *(float4*)(out + (size_t)g * 64 + c4) = o;
        }
    }
}

// Fallback: atomic epilogue (proven R1 path), pairE = {src, dst}
__global__ void __launch_bounds__(256)
k_compute(const unsigned short* __restrict__ featB,
          const unsigned short* __restrict__ Wt,
          const int2* __restrict__ pairE, const int* __restrict__ Pve,
          float* __restrict__ out) {
    const int t = blockIdx.x * 4 + (threadIdx.x >> 6);
    const int base = t * 64;
    const int total = Pve[16];
    if (base >= total) return;
    int r = 0;
    while (base >= Pve[r + 1]) ++r;
    const int validEnd = Pve[17 + r];
    const int lane = threadIdx.x & 63;
    const int quad = lane >> 4;
    const int l16 = lane & 15;

    const unsigned short* wr = Wt + (r << 12);
    short8 bfr[4][2];
    #pragma unroll
    for (int tn = 0; tn < 4; ++tn)
        #pragma unroll
        for (int ks = 0; ks < 2; ++ks)
            bfr[tn][ks] = *(const short8*)(wr + ((tn * 16 + l16) << 6) + ks * 32 + quad * 8);

    #pragma unroll
    for (int tm = 0; tm < 4; ++tm) {
        int row = base + tm * 16 + l16;
        int s = (row < validEnd) ? pairE[row].x : 0;
        const unsigned short* fp = featB + (s << 6) + quad * 8;
        short8 a0 = *(const short8*)(fp);
        short8 a1 = *(const short8*)(fp + 32);
        floatx4 cc[4];
        #pragma unroll
        for (int tn = 0; tn < 4; ++tn) {
            floatx4 c = {0.f, 0.f, 0.f, 0.f};
            c = __builtin_amdgcn_mfma_f32_16x16x32_bf16(a0, bfr[tn][0], c, 0, 0, 0);
            c = __builtin_amdgcn_mfma_f32_16x16x32_bf16(a1, bfr[tn][1], c, 0, 0, 0);
            cc[tn] = c;
        }
        int pos0 = base + tm * 16 + quad * 4;
        #pragma unroll
        for (int j = 0; j < 4; ++j) {
            if (pos0 + j < validEnd) {
                int dn = pairE[pos0 + j].y;
                float* op = out + (dn << 6) + l16;
                #pragma unroll
                for (int tn = 0; tn < 4; ++tn)
                    atomicAdd(op + tn * 16, cc[tn][j]);
            }
        }
    }
}

extern "C" void kernel_launch(void* const* d_in, const int* in_sizes, int n_in,
                              void* d_out, int out_size, void* d_ws, size_t ws_size,
                              hipStream_t stream) {
    const float* feat = (const float*)d_in[0];
    const float* W    = (const float*)d_in[1];
    const int* src    = (const int*)d_in[2];
    const int* dst    = (const int*)d_in[3];
    const int* et     = (const int*)d_in[4];
    float* out = (float*)d_out;
    char* ws = (char*)d_ws;

    unsigned short* featB = (unsigned short*)(ws);
    unsigned short* Wt    = (unsigned short*)(ws + 12800000);
    int* hist16   = (int*)(ws + 12931072);
    int* bbase16  = (int*)(ws + 12963840);
    int* Pve      = (int*)(ws + 12996608);
    int* hist391  = (int*)(ws + 12996864);
    int* bbase391 = (int*)(ws + 13764864);
    int* bstart   = (int*)(ws + 14532864);
    unsigned short* dloc = (unsigned short*)(ws + 14534464);
    int2* pairE   = (int2*)(ws + 16534464);
    unsigned short* msgE = (unsigned short*)(ws + 24542656);

    const int usePhases = (ws_size >= WS_NEED) ? 1 : 0;

    k_setup<<<SETUP_BLKS, 256, 0, stream>>>(feat, W, et, dst, featB, Wt, hist16, hist391);
    k_scan<<<1, 1024, 0, stream>>>(hist16, bbase16, Pve);

    if (usePhases) {
        k_bscanA<<<(NBKT + 3) / 4, 256, 0, stream>>>(hist391, bbase391, bstart);
        k_bscanB<<<1, 64, 0, stream>>>(bstart);
        k_scatter<<<NB, 256, 0, stream>>>(et, src, dst, bbase16, bbase391, bstart,
                                          pairE, dloc, 1);
        k_computeA<<<(MAXTILES + 3) / 4, 256, 0, stream>>>(featB, Wt, pairE, Pve, msgE);
        k_reduce<<<NBKT, 512, 0, stream>>>(msgE, dloc, bstart, out);
    } else {
        hipMemsetAsync(d_out, 0, (size_t)out_size * sizeof(float), stream);
        k_scatter<<<NB, 256, 0, stream>>>(et, src, dst, bbase16, bbase391, bstart,
                                          pairE, dloc, 0);
        k_compute<<<(MAXTILES + 3) / 4, 256, 0, stream>>>(featB, Wt, pairE, Pve, out);
    }
}

// Round 7
// 241.906 us; speedup vs baseline: 2.6280x; 2.6280x over previous
//
#include <hip/hip_runtime.h>
#include <hip/hip_bf16.h>
#include <stdint.h>

#define NNODES 100000
#define NEDGES 1000000
#define DIM 64
#define NRELS 16
#define EPB 2048
#define NB ((NEDGES + EPB - 1) / EPB)   /* 489 */
#define PADCAP (NEDGES + NRELS * 64)    /* 1001024 */
#define MAXTILES (PADCAP / 64)          /* 15641 */
#define NDN NNODES
#define BKT 256                          /* nodes per dst bucket */
#define NBKT ((NDN + BKT - 1) / BKT)     /* 391 */

// setup grid split
#define FEAT_BLKS 6250
#define W_BLKS 256
#define SETUP_BLKS (FEAT_BLKS + W_BLKS + NB)

// ws layout (bytes):
//   featB   @ 0          : ushort[NNODES*64]   -> 12,800,000
//   Wt      @ 12800000   : ushort[16*64*64]    -> 12,931,072
//   hist16  @ 12931072   : int[NB*16]          -> 12,963,840
//   bbase16 @ 12963840   : int[NB*16]          -> 12,996,608
//   Pve     @ 12996608   : int[33]             -> 12,996,864
//   hist391 @ 12996864   : int[NB*NBKT]        -> 13,764,864
//   bbase391@ 13764864   : int[NB*NBKT]        -> 14,532,864
//   bstart  @ 14532864   : int[NBKT+1]         -> 14,534,464
//   dnode   @ 14534464   : ushort[NEDGES]      -> 16,534,464
//   dnstart @ 16534464   : int[NBKT*256+1]     -> 16,935,232 (reserve 400,768)
//   remap   @ 16935232   : int[NEDGES]         -> 20,935,232
//   pairE   @ 20935232   : int2[PADCAP]        -> 28,943,424  {src, bpos|dst}
//   msgE    @ 28943424   : ushort[NEDGES*64]   -> 156,943,424
#define WS_NEED 156943424ull

using short8  = __attribute__((ext_vector_type(8))) short;
using floatx4 = __attribute__((ext_vector_type(4))) float;
using uintx4  = __attribute__((ext_vector_type(4))) unsigned int;

__device__ __forceinline__ unsigned short f2bf(float f) {
    union { float f; uint32_t u; } v; v.f = f;
    uint32_t u = v.u;
    return (unsigned short)((u + 0x7FFFu + ((u >> 16) & 1u)) >> 16);
}
__device__ __forceinline__ float bf2f(uint32_t u16) {
    union { uint32_t u; float f; } v; v.u = u16 << 16;
    return v.f;
}
__device__ __forceinline__ uint32_t pk2(float a, float b) {
    __hip_bfloat162 h = __float22bfloat162_rn(make_float2(a, b));
    union { __hip_bfloat162 h; uint32_t u; } v; v.h = h;
    return v.u;
}

// fused setup: feat->bf16, W->bf16 transposed, per-block rel hist + dst-bucket hist.
// NO global atomics.
__global__ void k_setup(const float* __restrict__ feat, const float* __restrict__ W,
                        const int* __restrict__ et, const int* __restrict__ dst,
                        unsigned short* __restrict__ featB, unsigned short* __restrict__ Wt,
                        int* __restrict__ hist16, int* __restrict__ hist391) {
    __shared__ int cnt16[16];
    __shared__ int cnt391[NBKT];
    const int b = blockIdx.x;
    if (b < FEAT_BLKS) {
        int i = (b * 256 + threadIdx.x) * 4;
        const float4 f = *(const float4*)(feat + i);
        ushort4 o;
        o.x = f2bf(f.x); o.y = f2bf(f.y); o.z = f2bf(f.z); o.w = f2bf(f.w);
        *(ushort4*)(featB + i) = o;
    } else if (b < FEAT_BLKS + W_BLKS) {
        int t = (b - FEAT_BLKS) * 256 + threadIdx.x;   // 65536 total
        int r = t >> 12, n = (t >> 6) & 63, k = t & 63;
        Wt[t] = f2bf(W[(r << 12) + (k << 6) + n]);     // Wt[r][n][k] = W[r][k][n]
    } else {
        const int bb = b - (FEAT_BLKS + W_BLKS);
        if (threadIdx.x < 16) cnt16[threadIdx.x] = 0;
        for (int t = threadIdx.x; t < NBKT; t += 256) cnt391[t] = 0;
        __syncthreads();
        int start = bb * EPB;
        int end = min(NEDGES, start + EPB);
        for (int i = start + threadIdx.x; i < end; i += 256) {
            atomicAdd(&cnt16[et[i]], 1);
            atomicAdd(&cnt391[dst[i] >> 8], 1);
        }
        __syncthreads();
        if (threadIdx.x < 16) hist16[bb * 16 + threadIdx.x] = cnt16[threadIdx.x];
        for (int t = threadIdx.x; t < NBKT; t += 256)
            hist391[bb * NBKT + t] = cnt391[t];
    }
}

// relation scan: 16 waves, wave w scans relation w over NB blocks
__global__ void k_scan(const int* __restrict__ hist, int* __restrict__ bbase,
                       int* __restrict__ Pve) {
    __shared__ int s_cnt[16];
    __shared__ int s_P[17];
    int w = threadIdx.x >> 6;
    int lane = threadIdx.x & 63;
    int carry = 0;
    for (int c = 0; c < NB; c += 64) {
        int idx = c + lane;
        int v = (idx < NB) ? hist[idx * 16 + w] : 0;
        int x = v;
        #pragma unroll
        for (int off = 1; off < 64; off <<= 1) {
            int y = __shfl_up(x, off);
            if (lane >= off) x += y;
        }
        if (idx < NB) bbase[idx * 16 + w] = carry + x - v;
        carry += __shfl(x, 63);
    }
    if (lane == 0) s_cnt[w] = carry;
    __syncthreads();
    if (threadIdx.x == 0) {
        int p = 0;
        for (int r = 0; r < 16; ++r) {
            s_P[r] = p;
            Pve[r] = p;
            Pve[17 + r] = p + s_cnt[r];
            p += (s_cnt[r] + 63) & ~63;
        }
        s_P[16] = p;
        Pve[16] = p;
    }
    __syncthreads();
    int pw = s_P[w];
    for (int idx = lane; idx < NB; idx += 64)
        bbase[idx * 16 + w] += pw;
}

// bucket scan A: one wave per bucket, exclusive over NB blocks; totals -> bstart[b]
__global__ void k_bscanA(const int* __restrict__ hist391, int* __restrict__ bbase391,
                         int* __restrict__ bstart) {
    int b = blockIdx.x * 4 + (threadIdx.x >> 6);
    int lane = threadIdx.x & 63;
    if (b >= NBKT) return;
    int carry = 0;
    for (int c = 0; c < NB; c += 64) {
        int idx = c + lane;
        int v = (idx < NB) ? hist391[idx * NBKT + b] : 0;
        int x = v;
        #pragma unroll
        for (int off = 1; off < 64; off <<= 1) {
            int y = __shfl_up(x, off);
            if (lane >= off) x += y;
        }
        if (idx < NB) bbase391[idx * NBKT + b] = carry + x - v;
        carry += __shfl(x, 63);
    }
    if (lane == 0) bstart[b] = carry;   // totals; exclusive-scanned in k_bscanB
}

// bucket scan B: parallel exclusive scan over NBKT totals (one block, 512 thr)
__global__ void k_bscanB(int* __restrict__ bstart) {
    __shared__ int wtot[8];
    int t = threadIdx.x;
    int v = (t < NBKT) ? bstart[t] : 0;
    int lane = t & 63, w = t >> 6;
    int x = v;
    #pragma unroll
    for (int off = 1; off < 64; off <<= 1) {
        int y = __shfl_up(x, off);
        if (lane >= off) x += y;
    }
    if (lane == 63) wtot[w] = x;
    __syncthreads();
    int woff = 0;
    for (int i = 0; i < w; ++i) woff += wtot[i];
    if (t <= NBKT) {
        // exclusive value for slot t; also writes sentinel at t==NBKT via last thread
        if (t < NBKT) bstart[t] = woff + x - v;
    }
    if (t == 511) {
        int total = 0;
        for (int i = 0; i < 8; ++i) total += wtot[i];
        bstart[NBKT] = total;
    }
}

// pairE[pos] = {src, bpos} (phases) or {src, dst} (fallback); dnode[bpos] = dst&255.
// Only LDS atomics.
__global__ void k_scatter(const int* __restrict__ et, const int* __restrict__ src,
                          const int* __restrict__ dst, const int* __restrict__ bbase16,
                          const int* __restrict__ bbase391, const int* __restrict__ bstart,
                          int2* __restrict__ pairE, unsigned short* __restrict__ dnode,
                          int buildPos) {
    __shared__ int base16[16];
    __shared__ int base391[NBKT];
    if (threadIdx.x < 16) base16[threadIdx.x] = bbase16[blockIdx.x * 16 + threadIdx.x];
    if (buildPos)
        for (int t = threadIdx.x; t < NBKT; t += 256)
            base391[t] = bbase391[blockIdx.x * NBKT + t] + bstart[t];
    __syncthreads();
    int start = blockIdx.x * EPB;
    int end = min(NEDGES, start + EPB);
    for (int i = start + threadIdx.x; i < end; i += 256) {
        int r = et[i];
        int pos = atomicAdd(&base16[r], 1);
        int d = dst[i];
        if (buildPos) {
            int bp = atomicAdd(&base391[d >> 8], 1);
            pairE[pos] = make_int2(src[i], bp);
            dnode[bp] = (unsigned short)(d & 255);
        } else {
            pairE[pos] = make_int2(src[i], d);
        }
    }
}

// refine bucket order into full dst sort: one block per bucket.
// remap[bp] = final dst-sorted position; dnstart[g] = segment start per node.
__global__ void __launch_bounds__(256)
k_bsort(const unsigned short* __restrict__ dnode, const int* __restrict__ bstart,
        int* __restrict__ remap, int* __restrict__ dnstart) {
    __shared__ int cnt[256];
    __shared__ int nodebase[256];
    __shared__ int wtot[4];
    const int b = blockIdx.x;
    const int start = bstart[b], end = bstart[b + 1];
    const int t = threadIdx.x;
    cnt[t] = 0;
    __syncthreads();
    for (int e = start + t; e < end; e += 256)
        atomicAdd(&cnt[dnode[e]], 1);
    __syncthreads();
    int v = cnt[t];
    int lane = t & 63, w = t >> 6;
    int x = v;
    #pragma unroll
    for (int off = 1; off < 64; off <<= 1) {
        int y = __shfl_up(x, off);
        if (lane >= off) x += y;
    }
    if (lane == 63) wtot[w] = x;
    __syncthreads();
    int woff = 0;
    for (int i = 0; i < w; ++i) woff += wtot[i];
    nodebase[t] = woff + x - v;          // exclusive scan
    cnt[t] = 0;
    __syncthreads();
    dnstart[b * 256 + t] = start + nodebase[t];
    for (int e = start + t; e < end; e += 256) {
        int node = dnode[e];
        int rk = atomicAdd(&cnt[node], 1);
        remap[e] = start + nodebase[node] + rk;
    }
}

// Phase A: per 64-edge tile (single relation), GEMM -> bf16 msg row at remap[bp] (NT stores)
__global__ void __launch_bounds__(256)
k_computeA(const unsigned short* __restrict__ featB,
           const unsigned short* __restrict__ Wt,
           const int2* __restrict__ pairE, const int* __restrict__ Pve,
           const int* __restrict__ remap,
           unsigned short* __restrict__ msgE) {
    __shared__ float lds[4][16 * 68];   // per-wave 16x64 transpose, stride 68
    const int w = threadIdx.x >> 6;
    const int t = blockIdx.x * 4 + w;
    const int base = t * 64;
    const int total = Pve[16];
    if (base >= total) return;
    int r = 0;
    while (base >= Pve[r + 1]) ++r;
    const int validEnd = Pve[17 + r];
    const int lane = threadIdx.x & 63;
    const int quad = lane >> 4;
    const int l16 = lane & 15;

    const unsigned short* wr = Wt + (r << 12);
    short8 bfr[4][2];
    #pragma unroll
    for (int tn = 0; tn < 4; ++tn)
        #pragma unroll
        for (int ks = 0; ks < 2; ++ks)
            bfr[tn][ks] = *(const short8*)(wr + ((tn * 16 + l16) << 6) + ks * 32 + quad * 8);

    const int rr = lane >> 2, seg = lane & 3;
    #pragma unroll
    for (int tm = 0; tm < 4; ++tm) {
        int row = base + tm * 16 + l16;
        int s = (row < validEnd) ? pairE[row].x : 0;
        const unsigned short* fp = featB + (s << 6) + quad * 8;
        short8 a0 = *(const short8*)(fp);
        short8 a1 = *(const short8*)(fp + 32);
        #pragma unroll
        for (int tn = 0; tn < 4; ++tn) {
            floatx4 c = {0.f, 0.f, 0.f, 0.f};
            c = __builtin_amdgcn_mfma_f32_16x16x32_bf16(a0, bfr[tn][0], c, 0, 0, 0);
            c = __builtin_amdgcn_mfma_f32_16x16x32_bf16(a1, bfr[tn][1], c, 0, 0, 0);
            #pragma unroll
            for (int j = 0; j < 4; ++j)
                lds[w][(quad * 4 + j) * 68 + tn * 16 + l16] = c[j];
        }
        // lane l handles output row (l>>2), 16-col segment (l&3)
        int rowi = base + tm * 16 + rr;
        int p = (rowi < validEnd) ? remap[pairE[rowi].y] : -1;
        if (p >= 0) {
            const float* lp = &lds[w][rr * 68 + seg * 16];
            uintx4 o0, o1;
            o0.x = pk2(lp[0],  lp[1]);  o0.y = pk2(lp[2],  lp[3]);
            o0.z = pk2(lp[4],  lp[5]);  o0.w = pk2(lp[6],  lp[7]);
            o1.x = pk2(lp[8],  lp[9]);  o1.y = pk2(lp[10], lp[11]);
            o1.z = pk2(lp[12], lp[13]); o1.w = pk2(lp[14], lp[15]);
            uintx4* op = (uintx4*)(msgE + (size_t)p * 64 + seg * 16);
            __builtin_nontemporal_store(o0, op);
            __builtin_nontemporal_store(o1, op + 1);
        }
    }
}

// Phase B: one wave per dst node; msgE segments contiguous (fully dst-sorted).
// 8 rows/iter: lane reads 16 B of row start+(lane>>3), cols (lane&7)*8.
__global__ void __launch_bounds__(256)
k_reduce(const unsigned short* __restrict__ msgE,
         const int* __restrict__ dnstart, float* __restrict__ out) {
    int n = blockIdx.x * 4 + (threadIdx.x >> 6);
    if (n >= NDN) return;
    int lane = threadIdx.x & 63;
    int start = dnstart[n];
    int end = dnstart[n + 1];
    int c8 = (lane & 7) * 8;   // ushort col offset
    float a0 = 0.f, a1 = 0.f, a2 = 0.f, a3 = 0.f;
    float a4 = 0.f, a5 = 0.f, a6 = 0.f, a7 = 0.f;
    for (int row = start + (lane >> 3); row < end; row += 8) {
        uintx4 v = *(const uintx4*)(msgE + (size_t)row * 64 + c8);
        a0 += bf2f(v.x & 0xffffu); a1 += bf2f(v.x >> 16);
        a2 += bf2f(v.y & 0xffffu); a3 += bf2f(v.y >> 16);
        a4 += bf2f(v.z & 0xffffu); a5 += bf2f(v.z >> 16);
        a6 += bf2f(v.w & 0xffffu); a7 += bf2f(v.w >> 16);
    }
    #pragma unroll
    for (int m = 8; m <= 32; m <<= 1) {
        a0 += __shfl_xor(a0, m); a1 += __shfl_xor(a1, m);
        a2 += __shfl_xor(a2, m); a3 += __shfl_xor(a3, m);
        a4 += __shfl_xor(a4, m); a5 += __shfl_xor(a5, m);
        a6 += __shfl_xor(a6, m); a7 += __shfl_xor(a7, m);
    }
    if (lane < 8) {
        float* op = out + (size_t)n * 64 + lane * 8;
        *(float4*)(op)     = make_float4(a0, a1, a2, a3);
        *(float4*)(op + 4) = make_float4(a4, a5, a6, a7);
    }
}

// Fallback: atomic epilogue (proven R1 path), pairE = {src, dst}
__global__ void __launch_bounds__(256)
k_compute(const unsigned short* __restrict__ featB,
          const unsigned short* __restrict__ Wt,
          const int2* __restrict__ pairE, const int* __restrict__ Pve,
          float* __restrict__ out) {
    const int t = blockIdx.x * 4 + (threadIdx.x >> 6);
    const int base = t * 64;
    const int total = Pve[16];
    if (base >= total) return;
    int r = 0;
    while (base >= Pve[r + 1]) ++r;
    const int validEnd = Pve[17 + r];
    const int lane = threadIdx.x & 63;
    const int quad = lane >> 4;
    const int l16 = lane & 15;

    const unsigned short* wr = Wt + (r << 12);
    short8 bfr[4][2];
    #pragma unroll
    for (int tn = 0; tn < 4; ++tn)
        #pragma unroll
        for (int ks = 0; ks < 2; ++ks)
            bfr[tn][ks] = *(const short8*)(wr + ((tn * 16 + l16) << 6) + ks * 32 + quad * 8);

    #pragma unroll
    for (int tm = 0; tm < 4; ++tm) {
        int row = base + tm * 16 + l16;
        int s = (row < validEnd) ? pairE[row].x : 0;
        const unsigned short* fp = featB + (s << 6) + quad * 8;
        short8 a0 = *(const short8*)(fp);
        short8 a1 = *(const short8*)(fp + 32);
        floatx4 cc[4];
        #pragma unroll
        for (int tn = 0; tn < 4; ++tn) {
            floatx4 c = {0.f, 0.f, 0.f, 0.f};
            c = __builtin_amdgcn_mfma_f32_16x16x32_bf16(a0, bfr[tn][0], c, 0, 0, 0);
            c = __builtin_amdgcn_mfma_f32_16x16x32_bf16(a1, bfr[tn][1], c, 0, 0, 0);
            cc[tn] = c;
        }
        int pos0 = base + tm * 16 + quad * 4;
        #pragma unroll
        for (int j = 0; j < 4; ++j) {
            if (pos0 + j < validEnd) {
                int dn = pairE[pos0 + j].y;
                float* op = out + (dn << 6) + l16;
                #pragma unroll
                for (int tn = 0; tn < 4; ++tn)
                    atomicAdd(op + tn * 16, cc[tn][j]);
            }
        }
    }
}

extern "C" void kernel_launch(void* const* d_in, const int* in_sizes, int n_in,
                              void* d_out, int out_size, void* d_ws, size_t ws_size,
                              hipStream_t stream) {
    const float* feat = (const float*)d_in[0];
    const float* W    = (const float*)d_in[1];
    const int* src    = (const int*)d_in[2];
    const int* dst    = (const int*)d_in[3];
    const int* et     = (const int*)d_in[4];
    float* out = (float*)d_out;
    char* ws = (char*)d_ws;

    unsigned short* featB = (unsigned short*)(ws);
    unsigned short* Wt    = (unsigned short*)(ws + 12800000);
    int* hist16   = (int*)(ws + 12931072);
    int* bbase16  = (int*)(ws + 12963840);
    int* Pve      = (int*)(ws + 12996608);
    int* hist391  = (int*)(ws + 12996864);
    int* bbase391 = (int*)(ws + 13764864);
    int* bstart   = (int*)(ws + 14532864);
    unsigned short* dnode = (unsigned short*)(ws + 14534464);
    int* dnstart  = (int*)(ws + 16534464);
    int* remap    = (int*)(ws + 16935232);
    int2* pairE   = (int2*)(ws + 20935232);
    unsigned short* msgE = (unsigned short*)(ws + 28943424);

    const int usePhases = (ws_size >= WS_NEED) ? 1 : 0;

    k_setup<<<SETUP_BLKS, 256, 0, stream>>>(feat, W, et, dst, featB, Wt, hist16, hist391);
    k_scan<<<1, 1024, 0, stream>>>(hist16, bbase16, Pve);

    if (usePhases) {
        k_bscanA<<<(NBKT + 3) / 4, 256, 0, stream>>>(hist391, bbase391, bstart);
        k_bscanB<<<1, 512, 0, stream>>>(bstart);
        k_scatter<<<NB, 256, 0, stream>>>(et, src, dst, bbase16, bbase391, bstart,
                                          pairE, dnode, 1);
        k_bsort<<<NBKT, 256, 0, stream>>>(dnode, bstart, remap, dnstart);
        k_computeA<<<(MAXTILES + 3) / 4, 256, 0, stream>>>(featB, Wt, pairE, Pve,
                                                           remap, msgE);
        k_reduce<<<(NDN + 3) / 4, 256, 0, stream>>>(msgE, dnstart, out);
    } else {
        hipMemsetAsync(d_out, 0, (size_t)out_size * sizeof(float), stream);
        k_scatter<<<NB, 256, 0, stream>>>(et, src, dst, bbase16, bbase391, bstart,
                                          pairE, dnode, 0);
        k_compute<<<(MAXTILES + 3) / 4, 256, 0, stream>>>(featB, Wt, pairE, Pve, out);
    }
}